// Round 1
// 984.863 us; speedup vs baseline: 1.0051x; 1.0051x over previous
//
#include <hip/hip_runtime.h>
#include <stdint.h>

// BitSwarmLinear: out = x @ sign(population.sum(axis=2))^T
//   x:          (4, 4096, 2048) fp32  -> A, M=16384, K=2048
//   population: (2048, 2048, 32) fp32 -> reduced+signed -> W (N=2048, K=2048), ±1
//   out:        (4, 4096, 2048) fp32  -> C, M x N
//
// v2 plan:
//   K1 swarm_reduce: pop -> W (bf16 ±1)            [memory-bound, ~85 us]
//   K2 a_to_bf16:    x fp32 -> bf16 (once)         [memory-bound, ~32 us]
//   K3 gemm_bt:      m97-structure MFMA GEMM, BOTH tiles via global_load_lds
//                    width=16, XCD-swizzled grid   [~870 TF target, ~160 us]

static constexpr int M_DIM = 16384;
static constexpr int N_DIM = 2048;
static constexpr int K_DIM = 2048;
static constexpr int SWARM = 32;

typedef __attribute__((ext_vector_type(8))) short short8;   // 8 x bf16 = 4 VGPRs
typedef __attribute__((ext_vector_type(4))) float f32x4;    // MFMA accumulator

// ---------------------------------------------------------------------------
// Kernel 1: swarm reduction + sign binarization.
// population is (N, K, 32): each output needs 32 contiguous floats (128 B).
// 8 lanes cooperate per output (coalesced float4 loads) + 3 xor-shuffles.
// sign(0) -> +1  ==>  (s >= 0) ? +1 : -1.  ±1.0 is exact in bf16.
// ---------------------------------------------------------------------------
__global__ __launch_bounds__(256) void swarm_reduce(const float4* __restrict__ pop4,
                                                    ushort* __restrict__ W) {
    const int tid = blockIdx.x * 256 + threadIdx.x;   // one float4 per thread
    float4 v = pop4[tid];
    float s = v.x + v.y + v.z + v.w;
    s += __shfl_xor(s, 1);
    s += __shfl_xor(s, 2);
    s += __shfl_xor(s, 4);
    if ((threadIdx.x & 7) == 0) {
        // +1.0 bf16 = 0x3F80, -1.0 bf16 = 0xBF80 (exact)
        W[tid >> 3] = (s >= 0.0f) ? (ushort)0x3F80 : (ushort)0xBF80;
    }
}

// fp32 -> bf16 round-to-nearest-even (no NaN inputs here)
__device__ __forceinline__ ushort f2bf(float f) {
    uint32_t u = __float_as_uint(f);
    u += 0x7FFFu + ((u >> 16) & 1u);
    return (ushort)(u >> 16);
}

// ---------------------------------------------------------------------------
// Kernel 2: one-shot fp32 -> bf16 conversion of x.
// Each thread: 2 float4 loads (32 B) -> 8 bf16 -> one 16 B store.
// 134 MB read + 67 MB write, pure streaming.
// ---------------------------------------------------------------------------
__global__ __launch_bounds__(256) void a_to_bf16(const float4* __restrict__ in,
                                                 ushort* __restrict__ out) {
    const int i = blockIdx.x * 256 + threadIdx.x;     // one 8-float group
    float4 v0 = in[2 * i];
    float4 v1 = in[2 * i + 1];
    union { ushort s[8]; uint4 u; } pk;
    pk.s[0] = f2bf(v0.x);
    pk.s[1] = f2bf(v0.y);
    pk.s[2] = f2bf(v0.z);
    pk.s[3] = f2bf(v0.w);
    pk.s[4] = f2bf(v1.x);
    pk.s[5] = f2bf(v1.y);
    pk.s[6] = f2bf(v1.z);
    pk.s[7] = f2bf(v1.w);
    *(uint4*)(&out[(size_t)i * 8]) = pk.u;            // 16 B aligned store
}

// ---------------------------------------------------------------------------
// Kernel 3: bf16 MFMA GEMM, C[m,n] = sum_k A[m,k] * W[n,k]  (B^T layout).
// m97 structure: 128x128 tile, BK=32, 4 waves (2x2), 4x4 16x16x32 MFMAs/wave.
// BOTH tiles staged with async global_load_lds width=16 (2 chunks each per
// thread per K-step) -- no VALU staging in the hot loop.
// Fragment layouts (guide §3, HW-verified):
//   A[m = lane&15][k = 8*(lane>>4) + j]     (short8)
//   B[k = 8*(lane>>4) + j][n = lane&15]     (short8, == W[n][k] row-major read)
//   D[i = 4*(lane>>4) + r][j = lane&15]     (f32x4)
// Grid: flat 2048 blocks, XCD-aware swizzle (2048 % 8 == 0 -> simple form is
// bijective), M-tile fastest within each XCD chunk so concurrent blocks on an
// XCD share the same 512 KB W panel in that XCD's L2.
// ---------------------------------------------------------------------------
#define BM 128
#define BN 128
#define BK 32

__global__ __launch_bounds__(256) void gemm_bt(const ushort* __restrict__ A,
                                               const ushort* __restrict__ B,
                                               float* __restrict__ C) {
    __shared__ ushort la[BM * BK];   // 8 KiB, A tile bf16, row-major [128][32]
    __shared__ ushort lb[BN * BK];   // 8 KiB, W tile,      row-major [128][32]

    const int t = threadIdx.x;

    // XCD-aware swizzle: XCD k owns logical ids [k*256, (k+1)*256)
    const int bid = blockIdx.x;                   // 0..2047
    const int swz = (bid & 7) * 256 + (bid >> 3); // bijective (2048 % 8 == 0)
    const int bm  = swz & 127;                    // M-tile index (fastest)
    const int bn  = swz >> 7;                     // N-tile index

    const int wave = t >> 6;
    const int lane = t & 63;
    const int wm   = (wave >> 1) * 64;    // wave sub-tile row offset
    const int wn   = (wave & 1) * 64;     // wave sub-tile col offset
    const int l16  = lane & 15;
    const int quad = lane >> 4;

    f32x4 acc[4][4];
    #pragma unroll
    for (int i = 0; i < 4; ++i)
        #pragma unroll
        for (int j = 0; j < 4; ++j)
            acc[i][j] = (f32x4){0.f, 0.f, 0.f, 0.f};

    const ushort* Abase = A + (size_t)(bm * BM) * K_DIM;
    const ushort* Bbase = B + (size_t)(bn * BN) * K_DIM;

    for (int k0 = 0; k0 < K_DIM; k0 += BK) {
        // ---- stage A and W tiles: async global->LDS, 16 B chunks ----
        // 512 chunks per tile, 256 threads -> 2 chunks each per tile.
        #pragma unroll
        for (int i = 0; i < 2; ++i) {
            const int c   = i * 256 + t;        // 16-byte chunk id
            const int row = c >> 2;             // 4 chunks per 64 B row
            const int kc  = (c & 3) * 8;
            __builtin_amdgcn_global_load_lds(
                (const __attribute__((address_space(1))) void*)
                    (Abase + (size_t)row * K_DIM + k0 + kc),
                (__attribute__((address_space(3))) void*)(&la[c * 8]),
                16, 0, 0);
            __builtin_amdgcn_global_load_lds(
                (const __attribute__((address_space(1))) void*)
                    (Bbase + (size_t)row * K_DIM + k0 + kc),
                (__attribute__((address_space(3))) void*)(&lb[c * 8]),
                16, 0, 0);
        }
        __syncthreads();

        // ---- fragments + 16 MFMAs ----
        short8 af[4], bf[4];
        #pragma unroll
        for (int tm = 0; tm < 4; ++tm)
            af[tm] = *(const short8*)(&la[(wm + tm * 16 + l16) * BK + quad * 8]);
        #pragma unroll
        for (int tn = 0; tn < 4; ++tn)
            bf[tn] = *(const short8*)(&lb[(wn + tn * 16 + l16) * BK + quad * 8]);
        #pragma unroll
        for (int tm = 0; tm < 4; ++tm)
            #pragma unroll
            for (int tn = 0; tn < 4; ++tn)
                acc[tm][tn] = __builtin_amdgcn_mfma_f32_16x16x32_bf16(
                    af[tm], bf[tn], acc[tm][tn], 0, 0, 0);
        __syncthreads();
    }

    // ---- epilogue: D[i = 4*quad + r][j = l16] ----
    #pragma unroll
    for (int tm = 0; tm < 4; ++tm) {
        #pragma unroll
        for (int tn = 0; tn < 4; ++tn) {
            const int row0 = bm * BM + wm + tm * 16 + quad * 4;
            const int col  = bn * BN + wn + tn * 16 + l16;
            #pragma unroll
            for (int r = 0; r < 4; ++r)
                C[(size_t)(row0 + r) * N_DIM + col] = acc[tm][tn][r];
        }
    }
}

extern "C" void kernel_launch(void* const* d_in, const int* in_sizes, int n_in,
                              void* d_out, int out_size, void* d_ws, size_t ws_size,
                              hipStream_t stream) {
    const float* x   = (const float*)d_in[0];   // (4,4096,2048) fp32
    const float* pop = (const float*)d_in[1];   // (2048,2048,32) fp32
    float* out = (float*)d_out;

    // workspace layout: [W bf16: 8 MiB][A bf16: 64 MiB]
    ushort* W   = (ushort*)d_ws;
    ushort* Abf = (ushort*)d_ws + (size_t)N_DIM * K_DIM;

    // Phase 1: reduce population -> W (±1 bf16)
    const int total4 = N_DIM * K_DIM * SWARM / 4;     // 33,554,432 float4 loads
    swarm_reduce<<<total4 / 256, 256, 0, stream>>>((const float4*)pop, W);

    // Phase 2: x fp32 -> bf16 (one pass)
    const int groups = M_DIM * K_DIM / 8;             // 4,194,304 8-float groups
    a_to_bf16<<<groups / 256, 256, 0, stream>>>((const float4*)x, Abf);

    // Phase 3: C = x @ W^T via bf16 MFMA
    gemm_bt<<<(M_DIM / BM) * (N_DIM / BN), 256, 0, stream>>>(Abf, W, out);
}

// Round 2
// 920.144 us; speedup vs baseline: 1.0757x; 1.0703x over previous
//
#include <hip/hip_runtime.h>
#include <stdint.h>

// BitSwarmLinear: out = x @ sign(population.sum(axis=2))^T
//   x:          (4, 4096, 2048) fp32  -> A, M=16384, K=2048
//   population: (2048, 2048, 32) fp32 -> reduced+signed -> W (N=2048, K=2048), ±1
//   out:        (4, 4096, 2048) fp32  -> C, M x N
//
// v3: GEMM ported to the 256^2 8-phase template (T2 st_16x32 swizzle +
//     T3/T4 phased schedule with counted vmcnt + T5 setprio).
//     K1 swarm_reduce and K2 a_to_bf16 unchanged (BW-bound).

static constexpr int M_DIM = 16384;
static constexpr int N_DIM = 2048;
static constexpr int K_DIM = 2048;
static constexpr int SWARM = 32;

typedef __attribute__((ext_vector_type(8))) short short8;   // 8 x bf16 = 4 VGPRs
typedef __attribute__((ext_vector_type(4))) float f32x4;    // MFMA accumulator

// ---------------------------------------------------------------------------
// Kernel 1: swarm reduction + sign binarization (memory-bound, ~85 us floor).
// ---------------------------------------------------------------------------
__global__ __launch_bounds__(256) void swarm_reduce(const float4* __restrict__ pop4,
                                                    ushort* __restrict__ W) {
    const int tid = blockIdx.x * 256 + threadIdx.x;   // one float4 per thread
    float4 v = pop4[tid];
    float s = v.x + v.y + v.z + v.w;
    s += __shfl_xor(s, 1);
    s += __shfl_xor(s, 2);
    s += __shfl_xor(s, 4);
    if ((threadIdx.x & 7) == 0) {
        // +1.0 bf16 = 0x3F80, -1.0 bf16 = 0xBF80 (exact)
        W[tid >> 3] = (s >= 0.0f) ? (ushort)0x3F80 : (ushort)0xBF80;
    }
}

// fp32 -> bf16 round-to-nearest-even (no NaN inputs here)
__device__ __forceinline__ ushort f2bf(float f) {
    uint32_t u = __float_as_uint(f);
    u += 0x7FFFu + ((u >> 16) & 1u);
    return (ushort)(u >> 16);
}

// ---------------------------------------------------------------------------
// Kernel 2: one-shot fp32 -> bf16 conversion of x (~33 us, streaming).
// ---------------------------------------------------------------------------
__global__ __launch_bounds__(256) void a_to_bf16(const float4* __restrict__ in,
                                                 ushort* __restrict__ out) {
    const int i = blockIdx.x * 256 + threadIdx.x;     // one 8-float group
    float4 v0 = in[2 * i];
    float4 v1 = in[2 * i + 1];
    union { ushort s[8]; uint4 u; } pk;
    pk.s[0] = f2bf(v0.x);
    pk.s[1] = f2bf(v0.y);
    pk.s[2] = f2bf(v0.z);
    pk.s[3] = f2bf(v0.w);
    pk.s[4] = f2bf(v1.x);
    pk.s[5] = f2bf(v1.y);
    pk.s[6] = f2bf(v1.z);
    pk.s[7] = f2bf(v1.w);
    *(uint4*)(&out[(size_t)i * 8]) = pk.u;            // 16 B aligned store
}

// ---------------------------------------------------------------------------
// Kernel 3: 256x256 8-phase bf16 MFMA GEMM (plain-HIP port of the verified
// m201 template).
//   - 512 threads = 8 waves in 2(M) x 4(N); per-wave output 128x64.
//   - LDS 128 KiB: 2 double-buffered [256][64] bf16 tiles for A and B.
//   - Staging: global_load_lds width=16, LINEAR LDS dest, st_16x32 swizzle
//     applied to the GLOBAL source address; ds_read applies the same XOR
//     involution:  off ^= ((off>>10)&1)<<5  (i.e. flip 32B unit when row&8).
//   - K-tile = 64, 4 phases/tile, 16 MFMA (16x16x32) per phase per wave.
//   - Prefetch of tile t+2 issued in phase 3 of tile t (buffer provably dead
//     after phase-2's closing barrier); boundary wait is counted vmcnt(8)
//     (the newest 8 loads = tile t+2 stay in flight) — never a drain in the
//     main loop.
// Fragment layouts (HW-verified, guide §3):
//   A[m = lane&15][k = 8*(lane>>4) + j]   B[k = 8*(lane>>4)+j][n = lane&15]
//   D[i = 4*(lane>>4) + r][j = lane&15]
// ---------------------------------------------------------------------------
#define BM 256
#define BN 256
#define BK 64
#define NT (K_DIM / BK)          // 32 K-tiles
#define TILE_E (BM * BK)         // 16384 ushort = 32 KiB per tile

__device__ __forceinline__ void stage_tile(const ushort* __restrict__ G,
                                           ushort* dst, int k0, int t) {
    #pragma unroll
    for (int i = 0; i < 4; ++i) {
        const int q  = (i * 512 + t) * 16;             // linear LDS byte offset
        const int sq = q ^ (((q >> 10) & 1) << 5);     // st_16x32 involution
        const int row  = sq >> 7;                      // 128 B per tile row
        const int colb = sq & 127;
        __builtin_amdgcn_global_load_lds(
            (const __attribute__((address_space(1))) void*)
                (G + (size_t)row * K_DIM + k0 + (colb >> 1)),
            (__attribute__((address_space(3))) void*)((char*)dst + q),
            16, 0, 0);
    }
}

// swizzled fragment read: base = tile base (char*), row = tile row,
// ks = k-substep (0/1), qoff = quad*16, flip = (l16&8)<<2
#define RD(base, row, ks, qoff, flip) \
    (*(const short8*)((base) + ((((row) * 128) + (ks) * 64 + (qoff)) ^ (flip))))

#define PHASE_OPEN()                                          \
    __builtin_amdgcn_s_barrier();                             \
    asm volatile("s_waitcnt lgkmcnt(0)" ::: "memory");        \
    __builtin_amdgcn_sched_barrier(0);                        \
    __builtin_amdgcn_s_setprio(1);

#define PHASE_CLOSE()                                         \
    __builtin_amdgcn_s_setprio(0);                            \
    __builtin_amdgcn_s_barrier();

#define MFMA_QUAD(mh, nh, BF)                                                 \
    _Pragma("unroll")                                                         \
    for (int mq = 0; mq < 4; ++mq) {                                          \
        _Pragma("unroll")                                                     \
        for (int nq = 0; nq < 2; ++nq) {                                      \
            acc[(mh)*4 + mq][(nh)*2 + nq] =                                   \
                __builtin_amdgcn_mfma_f32_16x16x32_bf16(                      \
                    af[mq][0], BF[nq][0], acc[(mh)*4 + mq][(nh)*2 + nq],      \
                    0, 0, 0);                                                 \
            acc[(mh)*4 + mq][(nh)*2 + nq] =                                   \
                __builtin_amdgcn_mfma_f32_16x16x32_bf16(                      \
                    af[mq][1], BF[nq][1], acc[(mh)*4 + mq][(nh)*2 + nq],      \
                    0, 0, 0);                                                 \
        }                                                                     \
    }

__global__ __launch_bounds__(512, 2) void gemm_bt(const ushort* __restrict__ A,
                                                  const ushort* __restrict__ B,
                                                  float* __restrict__ C) {
    // [buf0 A][buf0 B][buf1 A][buf1 B]  = 128 KiB
    __shared__ ushort lds[4 * TILE_E];

    const int t    = threadIdx.x;         // 0..511
    const int wave = t >> 6;
    const int lane = t & 63;
    const int wmid = wave >> 2;           // 0..1  (M)
    const int wnid = wave & 3;            // 0..3  (N)
    const int l16  = lane & 15;
    const int quad = lane >> 4;
    const int qoff = quad * 16;
    const int flip = (l16 & 8) << 2;      // row&8 is l16&8 for all frag rows

    // XCD-aware grid: blocks with bid%8==k share XCD k and the bn=k W panel
    // (1 MB, L2-resident); bm streams A panels through L3.
    const int bid = blockIdx.x;           // 0..511
    const int bn  = bid & 7;
    const int bm  = bid >> 3;

    const ushort* At = A + (size_t)(bm * BM) * K_DIM;
    const ushort* Bt = B + (size_t)(bn * BN) * K_DIM;

    f32x4 acc[8][4];
    #pragma unroll
    for (int i = 0; i < 8; ++i)
        #pragma unroll
        for (int j = 0; j < 4; ++j)
            acc[i][j] = (f32x4){0.f, 0.f, 0.f, 0.f};

    const int rA0 = wmid * 128 + l16;     // A frag base row (mh=0, mq=0)
    const int rB0 = wnid * 64 + l16;      // B frag base row (nh=0, nq=0)

    // ---- prologue: tiles 0 and 1 in flight, wait only for tile 0 ----
    stage_tile(At, lds + 0 * TILE_E, 0, t);
    stage_tile(Bt, lds + 1 * TILE_E, 0, t);
    stage_tile(At, lds + 2 * TILE_E, BK, t);
    stage_tile(Bt, lds + 3 * TILE_E, BK, t);
    asm volatile("s_waitcnt vmcnt(8)" ::: "memory");   // tile 0 landed
    __builtin_amdgcn_s_barrier();

    short8 af[4][2], b0[2][2], b1[2][2];

    for (int kt = 0; kt < NT; ++kt) {
        ushort*     curA = lds + (kt & 1) * 2 * TILE_E;
        ushort*     curB = curA + TILE_E;
        const char* cA   = (const char*)curA;
        const char* cB   = (const char*)curB;

        // ---- phase 0: (mh0, nh0) — read A(mh0) 8x + B(nh0) 4x ----
        #pragma unroll
        for (int mq = 0; mq < 4; ++mq) {
            af[mq][0] = RD(cA, rA0 + mq * 16, 0, qoff, flip);
            af[mq][1] = RD(cA, rA0 + mq * 16, 1, qoff, flip);
        }
        #pragma unroll
        for (int nq = 0; nq < 2; ++nq) {
            b0[nq][0] = RD(cB, rB0 + nq * 16, 0, qoff, flip);
            b0[nq][1] = RD(cB, rB0 + nq * 16, 1, qoff, flip);
        }
        PHASE_OPEN()
        MFMA_QUAD(0, 0, b0)
        PHASE_CLOSE()

        // ---- phase 1: (mh0, nh1) — read B(nh1) 4x, A reused ----
        #pragma unroll
        for (int nq = 0; nq < 2; ++nq) {
            b1[nq][0] = RD(cB, rB0 + 32 + nq * 16, 0, qoff, flip);
            b1[nq][1] = RD(cB, rB0 + 32 + nq * 16, 1, qoff, flip);
        }
        PHASE_OPEN()
        MFMA_QUAD(0, 1, b1)
        PHASE_CLOSE()

        // ---- phase 2: (mh1, nh1) — read A(mh1) 8x, B(nh1) reused ----
        #pragma unroll
        for (int mq = 0; mq < 4; ++mq) {
            af[mq][0] = RD(cA, rA0 + 64 + mq * 16, 0, qoff, flip);
            af[mq][1] = RD(cA, rA0 + 64 + mq * 16, 1, qoff, flip);
        }
        PHASE_OPEN()
        MFMA_QUAD(1, 1, b1)
        PHASE_CLOSE()

        // ---- phase 3: (mh1, nh0) — no reads; prefetch tile kt+2 into the
        // CURRENT buffer (all reads of it completed at phase-2's barrier),
        // then counted boundary wait: tile kt+1 landed, kt+2 stays in flight.
        if (kt + 2 < NT) {
            asm volatile("" ::: "memory");
            stage_tile(At, curA, (kt + 2) * BK, t);
            stage_tile(Bt, curB, (kt + 2) * BK, t);
        }
        PHASE_OPEN()
        MFMA_QUAD(1, 0, b0)
        __builtin_amdgcn_s_setprio(0);
        if (kt + 2 < NT) {
            asm volatile("s_waitcnt vmcnt(8)" ::: "memory");
        } else {
            asm volatile("s_waitcnt vmcnt(0)" ::: "memory");
        }
        __builtin_amdgcn_s_barrier();
    }

    // ---- epilogue: D[i = 4*quad + r][j = l16] ----
    const int row_base = bm * BM + wmid * 128 + quad * 4;
    const int col_base = bn * BN + wnid * 64 + l16;
    #pragma unroll
    for (int mi = 0; mi < 8; ++mi) {
        #pragma unroll
        for (int ni = 0; ni < 4; ++ni) {
            const int row0 = row_base + mi * 16;
            const int col  = col_base + ni * 16;
            #pragma unroll
            for (int r = 0; r < 4; ++r)
                C[(size_t)(row0 + r) * N_DIM + col] = acc[mi][ni][r];
        }
    }
}

extern "C" void kernel_launch(void* const* d_in, const int* in_sizes, int n_in,
                              void* d_out, int out_size, void* d_ws, size_t ws_size,
                              hipStream_t stream) {
    const float* x   = (const float*)d_in[0];   // (4,4096,2048) fp32
    const float* pop = (const float*)d_in[1];   // (2048,2048,32) fp32
    float* out = (float*)d_out;

    // workspace layout: [W bf16: 8 MiB][A bf16: 64 MiB]
    ushort* W   = (ushort*)d_ws;
    ushort* Abf = (ushort*)d_ws + (size_t)N_DIM * K_DIM;

    // Phase 1: reduce population -> W (±1 bf16)
    const int total4 = N_DIM * K_DIM * SWARM / 4;     // 33,554,432 float4 loads
    swarm_reduce<<<total4 / 256, 256, 0, stream>>>((const float4*)pop, W);

    // Phase 2: x fp32 -> bf16 (one pass)
    const int groups = M_DIM * K_DIM / 8;             // 4,194,304 8-float groups
    a_to_bf16<<<groups / 256, 256, 0, stream>>>((const float4*)x, Abf);

    // Phase 3: C = x @ W^T via 256^2 8-phase bf16 MFMA
    gemm_bt<<<(M_DIM / BM) * (N_DIM / BN), 512, 0, stream>>>(Abf, W, out);
}

// Round 3
// 904.709 us; speedup vs baseline: 1.0941x; 1.0171x over previous
//
#include <hip/hip_runtime.h>
#include <stdint.h>

// BitSwarmLinear: out = x @ sign(population.sum(axis=2))^T
//   x:          (4, 4096, 2048) fp32  -> A, M=16384, K=2048
//   population: (2048, 2048, 32) fp32 -> reduced+signed -> W (N=2048, K=2048), ±1
//   out:        (4, 4096, 2048) fp32  -> C, M x N
//
// v4: SWIZZLE FIX. v3's read swizzle was a 1-bit flip -> 8-way LDS bank
//     conflict on every ds_read_b128 (LDS-read-bound, ~740 TF). Replace with
//     the full 3-bit XOR (Guideline 4): byte ^= (row&7)<<4, applied BOTH on
//     the global_load_lds source and the ds_read side (rule #21). 16 lanes
//     now cover 8 distinct 16B slots (all 32 banks) with free 2-way aliasing.

static constexpr int M_DIM = 16384;
static constexpr int N_DIM = 2048;
static constexpr int K_DIM = 2048;
static constexpr int SWARM = 32;

typedef __attribute__((ext_vector_type(8))) short short8;   // 8 x bf16 = 4 VGPRs
typedef __attribute__((ext_vector_type(4))) float f32x4;    // MFMA accumulator

// ---------------------------------------------------------------------------
// Kernel 1: swarm reduction + sign binarization (memory-bound, ~85 us floor).
// ---------------------------------------------------------------------------
__global__ __launch_bounds__(256) void swarm_reduce(const float4* __restrict__ pop4,
                                                    ushort* __restrict__ W) {
    const int tid = blockIdx.x * 256 + threadIdx.x;   // one float4 per thread
    float4 v = pop4[tid];
    float s = v.x + v.y + v.z + v.w;
    s += __shfl_xor(s, 1);
    s += __shfl_xor(s, 2);
    s += __shfl_xor(s, 4);
    if ((threadIdx.x & 7) == 0) {
        // +1.0 bf16 = 0x3F80, -1.0 bf16 = 0xBF80 (exact)
        W[tid >> 3] = (s >= 0.0f) ? (ushort)0x3F80 : (ushort)0xBF80;
    }
}

// fp32 -> bf16 round-to-nearest-even (no NaN inputs here)
__device__ __forceinline__ ushort f2bf(float f) {
    uint32_t u = __float_as_uint(f);
    u += 0x7FFFu + ((u >> 16) & 1u);
    return (ushort)(u >> 16);
}

// ---------------------------------------------------------------------------
// Kernel 2: one-shot fp32 -> bf16 conversion of x (~33 us, streaming).
// ---------------------------------------------------------------------------
__global__ __launch_bounds__(256) void a_to_bf16(const float4* __restrict__ in,
                                                 ushort* __restrict__ out) {
    const int i = blockIdx.x * 256 + threadIdx.x;     // one 8-float group
    float4 v0 = in[2 * i];
    float4 v1 = in[2 * i + 1];
    union { ushort s[8]; uint4 u; } pk;
    pk.s[0] = f2bf(v0.x);
    pk.s[1] = f2bf(v0.y);
    pk.s[2] = f2bf(v0.z);
    pk.s[3] = f2bf(v0.w);
    pk.s[4] = f2bf(v1.x);
    pk.s[5] = f2bf(v1.y);
    pk.s[6] = f2bf(v1.z);
    pk.s[7] = f2bf(v1.w);
    *(uint4*)(&out[(size_t)i * 8]) = pk.u;            // 16 B aligned store
}

// ---------------------------------------------------------------------------
// Kernel 3: 256x256 8-phase bf16 MFMA GEMM.
//   - 512 threads = 8 waves in 2(M) x 4(N); per-wave output 128x64.
//   - LDS 128 KiB: double-buffered [256][64] bf16 tiles for A and B.
//   - Swizzle: byte ^= ((byte>>7)&7)<<4 -- XOR row bits 0-2 into the 16B-slot
//     bits. Involution, 16B-chunk-preserving. Applied on the GLOBAL source of
//     global_load_lds (LDS dest stays linear) and on every ds_read address.
//   - K-tile = 64, 4 phases/tile, 16 MFMA (16x16x32) per phase per wave.
//   - Prefetch tile kt+2 in phase 3 of tile kt; boundary wait vmcnt(8) only.
// Fragment layouts (HW-verified, guide §3):
//   A[m = lane&15][k = 8*(lane>>4) + j]   B[k = 8*(lane>>4)+j][n = lane&15]
//   D[i = 4*(lane>>4) + r][j = lane&15]
// ---------------------------------------------------------------------------
#define BM 256
#define BN 256
#define BK 64
#define NT (K_DIM / BK)          // 32 K-tiles
#define TILE_E (BM * BK)         // 16384 ushort = 32 KiB per tile

__device__ __forceinline__ void stage_tile(const ushort* __restrict__ G,
                                           ushort* dst, int k0, int t) {
    #pragma unroll
    for (int i = 0; i < 4; ++i) {
        const int q  = (i * 512 + t) * 16;             // linear LDS byte offset
        const int sq = q ^ (((q >> 7) & 7) << 4);      // 3-bit row->slot XOR
        const int row  = sq >> 7;                      // == q >> 7 (bits 7+ untouched)
        const int colb = sq & 127;
        __builtin_amdgcn_global_load_lds(
            (const __attribute__((address_space(1))) void*)
                (G + (size_t)row * K_DIM + k0 + (colb >> 1)),
            (__attribute__((address_space(3))) void*)((char*)dst + q),
            16, 0, 0);
    }
}

// swizzled fragment read: base = tile base (char*), row = tile row,
// ks = k-substep (0/1), qoff = quad*16, flip = (l16&7)<<4  (== (row&7)<<4
// for every fragment row used here: row = 16*const + l16)
#define RD(base, row, ks, qoff, flip) \
    (*(const short8*)((base) + ((row) * 128) + ((((ks) * 64) + (qoff)) ^ (flip))))

#define PHASE_OPEN()                                          \
    __builtin_amdgcn_s_barrier();                             \
    asm volatile("s_waitcnt lgkmcnt(0)" ::: "memory");        \
    __builtin_amdgcn_sched_barrier(0);                        \
    __builtin_amdgcn_s_setprio(1);

#define PHASE_CLOSE()                                         \
    __builtin_amdgcn_s_setprio(0);                            \
    __builtin_amdgcn_s_barrier();

#define MFMA_QUAD(mh, nh, BF)                                                 \
    _Pragma("unroll")                                                         \
    for (int mq = 0; mq < 4; ++mq) {                                          \
        _Pragma("unroll")                                                     \
        for (int nq = 0; nq < 2; ++nq) {                                      \
            acc[(mh)*4 + mq][(nh)*2 + nq] =                                   \
                __builtin_amdgcn_mfma_f32_16x16x32_bf16(                      \
                    af[mq][0], BF[nq][0], acc[(mh)*4 + mq][(nh)*2 + nq],      \
                    0, 0, 0);                                                 \
            acc[(mh)*4 + mq][(nh)*2 + nq] =                                   \
                __builtin_amdgcn_mfma_f32_16x16x32_bf16(                      \
                    af[mq][1], BF[nq][1], acc[(mh)*4 + mq][(nh)*2 + nq],      \
                    0, 0, 0);                                                 \
        }                                                                     \
    }

__global__ __launch_bounds__(512, 2) void gemm_bt(const ushort* __restrict__ A,
                                                  const ushort* __restrict__ B,
                                                  float* __restrict__ C) {
    // [buf0 A][buf0 B][buf1 A][buf1 B]  = 128 KiB
    __shared__ ushort lds[4 * TILE_E];

    const int t    = threadIdx.x;         // 0..511
    const int wave = t >> 6;
    const int lane = t & 63;
    const int wmid = wave >> 2;           // 0..1  (M)
    const int wnid = wave & 3;            // 0..3  (N)
    const int l16  = lane & 15;
    const int quad = lane >> 4;
    const int qoff = quad * 16;
    const int flip = (l16 & 7) << 4;      // row&7 == l16&7 for all frag rows

    // XCD-aware grid: blocks with bid%8==k share XCD k and the bn=k W panel
    // (1 MB, L2-resident); bm streams A panels through L3.
    const int bid = blockIdx.x;           // 0..511
    const int bn  = bid & 7;
    const int bm  = bid >> 3;

    const ushort* At = A + (size_t)(bm * BM) * K_DIM;
    const ushort* Bt = B + (size_t)(bn * BN) * K_DIM;

    f32x4 acc[8][4];
    #pragma unroll
    for (int i = 0; i < 8; ++i)
        #pragma unroll
        for (int j = 0; j < 4; ++j)
            acc[i][j] = (f32x4){0.f, 0.f, 0.f, 0.f};

    const int rA0 = wmid * 128 + l16;     // A frag base row (mh=0, mq=0)
    const int rB0 = wnid * 64 + l16;      // B frag base row (nh=0, nq=0)

    // ---- prologue: tiles 0 and 1 in flight, wait only for tile 0 ----
    stage_tile(At, lds + 0 * TILE_E, 0, t);
    stage_tile(Bt, lds + 1 * TILE_E, 0, t);
    stage_tile(At, lds + 2 * TILE_E, BK, t);
    stage_tile(Bt, lds + 3 * TILE_E, BK, t);
    asm volatile("s_waitcnt vmcnt(8)" ::: "memory");   // tile 0 landed
    __builtin_amdgcn_s_barrier();

    short8 af[4][2], b0[2][2], b1[2][2];

    for (int kt = 0; kt < NT; ++kt) {
        ushort*     curA = lds + (kt & 1) * 2 * TILE_E;
        ushort*     curB = curA + TILE_E;
        const char* cA   = (const char*)curA;
        const char* cB   = (const char*)curB;

        // ---- phase 0: (mh0, nh0) — read A(mh0) 8x + B(nh0) 4x ----
        #pragma unroll
        for (int mq = 0; mq < 4; ++mq) {
            af[mq][0] = RD(cA, rA0 + mq * 16, 0, qoff, flip);
            af[mq][1] = RD(cA, rA0 + mq * 16, 1, qoff, flip);
        }
        #pragma unroll
        for (int nq = 0; nq < 2; ++nq) {
            b0[nq][0] = RD(cB, rB0 + nq * 16, 0, qoff, flip);
            b0[nq][1] = RD(cB, rB0 + nq * 16, 1, qoff, flip);
        }
        PHASE_OPEN()
        MFMA_QUAD(0, 0, b0)
        PHASE_CLOSE()

        // ---- phase 1: (mh0, nh1) — read B(nh1) 4x, A reused ----
        #pragma unroll
        for (int nq = 0; nq < 2; ++nq) {
            b1[nq][0] = RD(cB, rB0 + 32 + nq * 16, 0, qoff, flip);
            b1[nq][1] = RD(cB, rB0 + 32 + nq * 16, 1, qoff, flip);
        }
        PHASE_OPEN()
        MFMA_QUAD(0, 1, b1)
        PHASE_CLOSE()

        // ---- phase 2: (mh1, nh1) — read A(mh1) 8x, B(nh1) reused ----
        #pragma unroll
        for (int mq = 0; mq < 4; ++mq) {
            af[mq][0] = RD(cA, rA0 + 64 + mq * 16, 0, qoff, flip);
            af[mq][1] = RD(cA, rA0 + 64 + mq * 16, 1, qoff, flip);
        }
        PHASE_OPEN()
        MFMA_QUAD(1, 1, b1)
        PHASE_CLOSE()

        // ---- phase 3: (mh1, nh0) — no reads; prefetch tile kt+2 into the
        // CURRENT buffer (all reads of it completed at phase-2's barrier),
        // then counted boundary wait: tile kt+1 landed, kt+2 stays in flight.
        if (kt + 2 < NT) {
            asm volatile("" ::: "memory");
            stage_tile(At, curA, (kt + 2) * BK, t);
            stage_tile(Bt, curB, (kt + 2) * BK, t);
        }
        PHASE_OPEN()
        MFMA_QUAD(1, 0, b0)
        __builtin_amdgcn_s_setprio(0);
        if (kt + 2 < NT) {
            asm volatile("s_waitcnt vmcnt(8)" ::: "memory");
        } else {
            asm volatile("s_waitcnt vmcnt(0)" ::: "memory");
        }
        __builtin_amdgcn_s_barrier();
    }

    // ---- epilogue: D[i = 4*quad + r][j = l16] ----
    const int row_base = bm * BM + wmid * 128 + quad * 4;
    const int col_base = bn * BN + wnid * 64 + l16;
    #pragma unroll
    for (int mi = 0; mi < 8; ++mi) {
        #pragma unroll
        for (int ni = 0; ni < 4; ++ni) {
            const int row0 = row_base + mi * 16;
            const int col  = col_base + ni * 16;
            #pragma unroll
            for (int r = 0; r < 4; ++r)
                C[(size_t)(row0 + r) * N_DIM + col] = acc[mi][ni][r];
        }
    }
}

extern "C" void kernel_launch(void* const* d_in, const int* in_sizes, int n_in,
                              void* d_out, int out_size, void* d_ws, size_t ws_size,
                              hipStream_t stream) {
    const float* x   = (const float*)d_in[0];   // (4,4096,2048) fp32
    const float* pop = (const float*)d_in[1];   // (2048,2048,32) fp32
    float* out = (float*)d_out;

    // workspace layout: [W bf16: 8 MiB][A bf16: 64 MiB]
    ushort* W   = (ushort*)d_ws;
    ushort* Abf = (ushort*)d_ws + (size_t)N_DIM * K_DIM;

    // Phase 1: reduce population -> W (±1 bf16)
    const int total4 = N_DIM * K_DIM * SWARM / 4;     // 33,554,432 float4 loads
    swarm_reduce<<<total4 / 256, 256, 0, stream>>>((const float4*)pop, W);

    // Phase 2: x fp32 -> bf16 (one pass)
    const int groups = M_DIM * K_DIM / 8;             // 4,194,304 8-float groups
    a_to_bf16<<<groups / 256, 256, 0, stream>>>((const float4*)x, Abf);

    // Phase 3: C = x @ W^T via 256^2 8-phase bf16 MFMA
    gemm_bt<<<(M_DIM / BM) * (N_DIM / BN), 512, 0, stream>>>(Abf, W, out);
}

// Round 4
// 900.364 us; speedup vs baseline: 1.0994x; 1.0048x over previous
//
#include <hip/hip_runtime.h>
#include <stdint.h>

// BitSwarmLinear: out = x @ sign(population.sum(axis=2))^T
//   x:          (4, 4096, 2048) fp32  -> A, M=16384, K=2048
//   population: (2048, 2048, 32) fp32 -> reduced+signed -> W (N=2048, K=2048), ±1
//   out:        (4, 4096, 2048) fp32  -> C, M x N
//
// v5: FINE-GRAINED STAGING INTERLEAVE (m196 lever). v4 batched all 8 prefetch
//     loads into phase 3 (memory pipe idle phases 0-2, then burst). Now:
//     B-prefetch (4 loads) issues in the phase-2 read region (curB's last
//     reader is phase 1 -> its close barrier proves the buffer dead),
//     A-prefetch (4 loads) in the phase-3 region (curA's last reader is
//     phase 2). Issue order ...kt+1-B, kt+1-A, kt+2-B, kt+2-A keeps the
//     boundary vmcnt(8) exact. Everything else unchanged from v4.

static constexpr int M_DIM = 16384;
static constexpr int N_DIM = 2048;
static constexpr int K_DIM = 2048;
static constexpr int SWARM = 32;

typedef __attribute__((ext_vector_type(8))) short short8;   // 8 x bf16 = 4 VGPRs
typedef __attribute__((ext_vector_type(4))) float f32x4;    // MFMA accumulator

// ---------------------------------------------------------------------------
// Kernel 1: swarm reduction + sign binarization (memory-bound, ~85 us floor).
// ---------------------------------------------------------------------------
__global__ __launch_bounds__(256) void swarm_reduce(const float4* __restrict__ pop4,
                                                    ushort* __restrict__ W) {
    const int tid = blockIdx.x * 256 + threadIdx.x;   // one float4 per thread
    float4 v = pop4[tid];
    float s = v.x + v.y + v.z + v.w;
    s += __shfl_xor(s, 1);
    s += __shfl_xor(s, 2);
    s += __shfl_xor(s, 4);
    if ((threadIdx.x & 7) == 0) {
        // +1.0 bf16 = 0x3F80, -1.0 bf16 = 0xBF80 (exact)
        W[tid >> 3] = (s >= 0.0f) ? (ushort)0x3F80 : (ushort)0xBF80;
    }
}

// fp32 -> bf16 round-to-nearest-even (no NaN inputs here)
__device__ __forceinline__ ushort f2bf(float f) {
    uint32_t u = __float_as_uint(f);
    u += 0x7FFFu + ((u >> 16) & 1u);
    return (ushort)(u >> 16);
}

// ---------------------------------------------------------------------------
// Kernel 2: one-shot fp32 -> bf16 conversion of x (~33 us, streaming).
// ---------------------------------------------------------------------------
__global__ __launch_bounds__(256) void a_to_bf16(const float4* __restrict__ in,
                                                 ushort* __restrict__ out) {
    const int i = blockIdx.x * 256 + threadIdx.x;     // one 8-float group
    float4 v0 = in[2 * i];
    float4 v1 = in[2 * i + 1];
    union { ushort s[8]; uint4 u; } pk;
    pk.s[0] = f2bf(v0.x);
    pk.s[1] = f2bf(v0.y);
    pk.s[2] = f2bf(v0.z);
    pk.s[3] = f2bf(v0.w);
    pk.s[4] = f2bf(v1.x);
    pk.s[5] = f2bf(v1.y);
    pk.s[6] = f2bf(v1.z);
    pk.s[7] = f2bf(v1.w);
    *(uint4*)(&out[(size_t)i * 8]) = pk.u;            // 16 B aligned store
}

// ---------------------------------------------------------------------------
// Kernel 3: 256x256 8-phase bf16 MFMA GEMM.
//   - 512 threads = 8 waves in 2(M) x 4(N); per-wave output 128x64.
//   - LDS 128 KiB: double-buffered [256][64] bf16 tiles for A and B.
//   - Swizzle: byte ^= ((byte>>7)&7)<<4, applied on the GLOBAL source of
//     global_load_lds (LDS dest linear) and on every ds_read address.
//   - K-tile = 64, 4 phases/tile, 16 MFMA (16x16x32) per phase per wave.
//   - Prefetch tile kt+2 SPREAD: B in phase-2 region, A in phase-3 region;
//     boundary wait vmcnt(8) only (tile kt+2's 8 loads stay in flight).
// Fragment layouts (HW-verified, guide §3):
//   A[m = lane&15][k = 8*(lane>>4) + j]   B[k = 8*(lane>>4)+j][n = lane&15]
//   D[i = 4*(lane>>4) + r][j = lane&15]
// ---------------------------------------------------------------------------
#define BM 256
#define BN 256
#define BK 64
#define NT (K_DIM / BK)          // 32 K-tiles
#define TILE_E (BM * BK)         // 16384 ushort = 32 KiB per tile

__device__ __forceinline__ void stage_tile(const ushort* __restrict__ G,
                                           ushort* dst, int k0, int t) {
    #pragma unroll
    for (int i = 0; i < 4; ++i) {
        const int q  = (i * 512 + t) * 16;             // linear LDS byte offset
        const int sq = q ^ (((q >> 7) & 7) << 4);      // 3-bit row->slot XOR
        const int row  = sq >> 7;                      // == q >> 7 (bits 7+ untouched)
        const int colb = sq & 127;
        __builtin_amdgcn_global_load_lds(
            (const __attribute__((address_space(1))) void*)
                (G + (size_t)row * K_DIM + k0 + (colb >> 1)),
            (__attribute__((address_space(3))) void*)((char*)dst + q),
            16, 0, 0);
    }
}

// swizzled fragment read: base = tile base (char*), row = tile row,
// ks = k-substep (0/1), qoff = quad*16, flip = (l16&7)<<4  (== (row&7)<<4
// for every fragment row used here: row = 16*const + l16)
#define RD(base, row, ks, qoff, flip) \
    (*(const short8*)((base) + ((row) * 128) + ((((ks) * 64) + (qoff)) ^ (flip))))

#define PHASE_OPEN()                                          \
    __builtin_amdgcn_s_barrier();                             \
    asm volatile("s_waitcnt lgkmcnt(0)" ::: "memory");        \
    __builtin_amdgcn_sched_barrier(0);                        \
    __builtin_amdgcn_s_setprio(1);

#define PHASE_CLOSE()                                         \
    __builtin_amdgcn_s_setprio(0);                            \
    __builtin_amdgcn_s_barrier();

#define MFMA_QUAD(mh, nh, BF)                                                 \
    _Pragma("unroll")                                                         \
    for (int mq = 0; mq < 4; ++mq) {                                          \
        _Pragma("unroll")                                                     \
        for (int nq = 0; nq < 2; ++nq) {                                      \
            acc[(mh)*4 + mq][(nh)*2 + nq] =                                   \
                __builtin_amdgcn_mfma_f32_16x16x32_bf16(                      \
                    af[mq][0], BF[nq][0], acc[(mh)*4 + mq][(nh)*2 + nq],      \
                    0, 0, 0);                                                 \
            acc[(mh)*4 + mq][(nh)*2 + nq] =                                   \
                __builtin_amdgcn_mfma_f32_16x16x32_bf16(                      \
                    af[mq][1], BF[nq][1], acc[(mh)*4 + mq][(nh)*2 + nq],      \
                    0, 0, 0);                                                 \
        }                                                                     \
    }

__global__ __launch_bounds__(512, 2) void gemm_bt(const ushort* __restrict__ A,
                                                  const ushort* __restrict__ B,
                                                  float* __restrict__ C) {
    // [buf0 A][buf0 B][buf1 A][buf1 B]  = 128 KiB
    __shared__ ushort lds[4 * TILE_E];

    const int t    = threadIdx.x;         // 0..511
    const int wave = t >> 6;
    const int lane = t & 63;
    const int wmid = wave >> 2;           // 0..1  (M)
    const int wnid = wave & 3;            // 0..3  (N)
    const int l16  = lane & 15;
    const int quad = lane >> 4;
    const int qoff = quad * 16;
    const int flip = (l16 & 7) << 4;      // row&7 == l16&7 for all frag rows

    // XCD-aware grid: blocks with bid%8==k share XCD k and the bn=k W panel
    // (1 MB, L2-resident); bm streams A panels through L3.
    const int bid = blockIdx.x;           // 0..511
    const int bn  = bid & 7;
    const int bm  = bid >> 3;

    const ushort* At = A + (size_t)(bm * BM) * K_DIM;
    const ushort* Bt = B + (size_t)(bn * BN) * K_DIM;

    f32x4 acc[8][4];
    #pragma unroll
    for (int i = 0; i < 8; ++i)
        #pragma unroll
        for (int j = 0; j < 4; ++j)
            acc[i][j] = (f32x4){0.f, 0.f, 0.f, 0.f};

    const int rA0 = wmid * 128 + l16;     // A frag base row (mh=0, mq=0)
    const int rB0 = wnid * 64 + l16;      // B frag base row (nh=0, nq=0)

    // ---- prologue: tiles 0 and 1 in flight, wait only for tile 0 ----
    stage_tile(At, lds + 0 * TILE_E, 0, t);
    stage_tile(Bt, lds + 1 * TILE_E, 0, t);
    stage_tile(Bt, lds + 3 * TILE_E, BK, t);   // tile1 B first (matches loop order)
    stage_tile(At, lds + 2 * TILE_E, BK, t);   // tile1 A
    asm volatile("s_waitcnt vmcnt(8)" ::: "memory");   // tile 0 landed
    __builtin_amdgcn_s_barrier();

    short8 af[4][2], b0[2][2], b1[2][2];

    for (int kt = 0; kt < NT; ++kt) {
        ushort*     curA = lds + (kt & 1) * 2 * TILE_E;
        ushort*     curB = curA + TILE_E;
        const char* cA   = (const char*)curA;
        const char* cB   = (const char*)curB;
        const bool  pf   = (kt + 2 < NT);

        // ---- phase 0: (mh0, nh0) — read A(mh0) 8x + B(nh0) 4x ----
        #pragma unroll
        for (int mq = 0; mq < 4; ++mq) {
            af[mq][0] = RD(cA, rA0 + mq * 16, 0, qoff, flip);
            af[mq][1] = RD(cA, rA0 + mq * 16, 1, qoff, flip);
        }
        #pragma unroll
        for (int nq = 0; nq < 2; ++nq) {
            b0[nq][0] = RD(cB, rB0 + nq * 16, 0, qoff, flip);
            b0[nq][1] = RD(cB, rB0 + nq * 16, 1, qoff, flip);
        }
        PHASE_OPEN()
        MFMA_QUAD(0, 0, b0)
        PHASE_CLOSE()

        // ---- phase 1: (mh0, nh1) — read B(nh1) 4x, A reused ----
        #pragma unroll
        for (int nq = 0; nq < 2; ++nq) {
            b1[nq][0] = RD(cB, rB0 + 32 + nq * 16, 0, qoff, flip);
            b1[nq][1] = RD(cB, rB0 + 32 + nq * 16, 1, qoff, flip);
        }
        PHASE_OPEN()
        MFMA_QUAD(0, 1, b1)
        PHASE_CLOSE()

        // ---- phase 2: (mh1, nh1) — read A(mh1) 8x; ISSUE B-prefetch kt+2.
        // curB's last reader was phase 1; its close barrier proves all waves'
        // b1 reads complete, so overwriting curB is safe from here on.
        #pragma unroll
        for (int mq = 0; mq < 4; ++mq) {
            af[mq][0] = RD(cA, rA0 + 64 + mq * 16, 0, qoff, flip);
            af[mq][1] = RD(cA, rA0 + 64 + mq * 16, 1, qoff, flip);
        }
        if (pf) {
            asm volatile("" ::: "memory");
            stage_tile(Bt, curB, (kt + 2) * BK, t);
        }
        PHASE_OPEN()
        MFMA_QUAD(1, 1, b1)
        PHASE_CLOSE()

        // ---- phase 3: (mh1, nh0) — ISSUE A-prefetch kt+2 (curA's last
        // reader was phase 2); boundary wait: kt+1 landed, kt+2 in flight.
        if (pf) {
            asm volatile("" ::: "memory");
            stage_tile(At, curA, (kt + 2) * BK, t);
        }
        PHASE_OPEN()
        MFMA_QUAD(1, 0, b0)
        __builtin_amdgcn_s_setprio(0);
        if (pf) {
            asm volatile("s_waitcnt vmcnt(8)" ::: "memory");
        } else {
            asm volatile("s_waitcnt vmcnt(0)" ::: "memory");
        }
        __builtin_amdgcn_s_barrier();
    }

    // ---- epilogue: D[i = 4*quad + r][j = l16] ----
    const int row_base = bm * BM + wmid * 128 + quad * 4;
    const int col_base = bn * BN + wnid * 64 + l16;
    #pragma unroll
    for (int mi = 0; mi < 8; ++mi) {
        #pragma unroll
        for (int ni = 0; ni < 4; ++ni) {
            const int row0 = row_base + mi * 16;
            const int col  = col_base + ni * 16;
            #pragma unroll
            for (int r = 0; r < 4; ++r)
                C[(size_t)(row0 + r) * N_DIM + col] = acc[mi][ni][r];
        }
    }
}

extern "C" void kernel_launch(void* const* d_in, const int* in_sizes, int n_in,
                              void* d_out, int out_size, void* d_ws, size_t ws_size,
                              hipStream_t stream) {
    const float* x   = (const float*)d_in[0];   // (4,4096,2048) fp32
    const float* pop = (const float*)d_in[1];   // (2048,2048,32) fp32
    float* out = (float*)d_out;

    // workspace layout: [W bf16: 8 MiB][A bf16: 64 MiB]
    ushort* W   = (ushort*)d_ws;
    ushort* Abf = (ushort*)d_ws + (size_t)N_DIM * K_DIM;

    // Phase 1: reduce population -> W (±1 bf16)
    const int total4 = N_DIM * K_DIM * SWARM / 4;     // 33,554,432 float4 loads
    swarm_reduce<<<total4 / 256, 256, 0, stream>>>((const float4*)pop, W);

    // Phase 2: x fp32 -> bf16 (one pass)
    const int groups = M_DIM * K_DIM / 8;             // 4,194,304 8-float groups
    a_to_bf16<<<groups / 256, 256, 0, stream>>>((const float4*)x, Abf);

    // Phase 3: C = x @ W^T via 256^2 8-phase bf16 MFMA
    gemm_bt<<<(M_DIM / BM) * (N_DIM / BN), 512, 0, stream>>>(Abf, W, out);
}